// Round 4
// baseline (300.184 us; speedup 1.0000x reference)
//
#include <hip/hip_runtime.h>

typedef __attribute__((ext_vector_type(8))) short short8;
typedef __attribute__((ext_vector_type(4))) short short4_t;
typedef __attribute__((ext_vector_type(4))) float f32x4;

#define NEGBIG -1e10f

__device__ __forceinline__ unsigned short f2bf(float x) {
  unsigned int u = __float_as_uint(x);
  u += 0x7FFFu + ((u >> 16) & 1u);          // round-to-nearest-even
  return (unsigned short)(u >> 16);
}

__device__ __forceinline__ float4 mul4(float4 a, float s) {
  float4 r; r.x = a.x*s; r.y = a.y*s; r.z = a.z*s; r.w = a.w*s; return r;
}
__device__ __forceinline__ float4 add4(float4 a, float4 b) {
  float4 r; r.x = a.x+b.x; r.y = a.y+b.y; r.z = a.z+b.z; r.w = a.w+b.w; return r;
}
// a + c*x
__device__ __forceinline__ float4 fma4(float4 x, float c, float4 a) {
  float4 r;
  r.x = a.x + c*x.x; r.y = a.y + c*x.y;
  r.z = a.z + c*x.z; r.w = a.w + c*x.w;
  return r;
}

// ---------------- pooling kernel (online softmax, 4-token groups) ----------
// One block (4 waves) per (side, b, f). Each wave owns 16 tokens in 4 groups
// of 4: batched loads (12 float4 issued together), 4 pipelined shuffle-reduce
// chains, group softmax, ONE merge with running state per group. This breaks
// the per-token serial latency chain that limited the previous version.
__global__ __launch_bounds__(256, 4) void pool_kernel(
    const float* __restrict__ left, const float* __restrict__ right,
    const float* __restrict__ femb_l, const float* __restrict__ femb_r,
    const float* __restrict__ empty_attr,
    unsigned short* __restrict__ concat)   // [B, 8, 768] bf16
{
  int bid  = blockIdx.x;      // 0..2047
  int side = bid >> 10;       // 0 = left, 1 = right
  int rem  = bid & 1023;      // b*4 + f
  int f    = rem & 3;
  int b    = rem >> 2;
  const float* v    = (side ? right : left) + (size_t)rem * 64 * 768;
  const float* femb = (side ? femb_r : femb_l) + f * 768;

  int tid = threadIdx.x, wave = tid >> 6, lane = tid & 63;

  const float4* fp = (const float4*)femb;
  float4 f0 = fp[lane], f1 = fp[lane + 64], f2 = fp[lane + 128];

  float4 a0 = {0,0,0,0}, a1 = {0,0,0,0}, a2 = {0,0,0,0};
  float m = -3.0e38f, s = 0.f;
  int wnz = 0;

  const float4* vp = (const float4*)(v + (size_t)wave * 16 * 768);

  #pragma unroll
  for (int g = 0; g < 4; ++g) {
    // batched loads for 4 tokens (issued together; compiler can hoist the
    // next group's batch above this group's compute)
    float4 x0[4], x1[4], x2[4];
    #pragma unroll
    for (int t = 0; t < 4; ++t) {
      const float4* tp = vp + (g * 4 + t) * 192 + lane;
      x0[t] = tp[0]; x1[t] = tp[64]; x2[t] = tp[128];
    }
    // 4 independent dot partials + bit-OR nonzero detection
    float d[4]; unsigned nzb[4];
    #pragma unroll
    for (int t = 0; t < 4; ++t) {
      float4 y0 = x0[t], y1 = x1[t], y2 = x2[t];
      d[t] = y0.x*f0.x + y0.y*f0.y + y0.z*f0.z + y0.w*f0.w
           + y1.x*f1.x + y1.y*f1.y + y1.z*f1.z + y1.w*f1.w
           + y2.x*f2.x + y2.y*f2.y + y2.z*f2.z + y2.w*f2.w;
      nzb[t] = __float_as_uint(y0.x) | __float_as_uint(y0.y)
             | __float_as_uint(y0.z) | __float_as_uint(y0.w)
             | __float_as_uint(y1.x) | __float_as_uint(y1.y)
             | __float_as_uint(y1.z) | __float_as_uint(y1.w)
             | __float_as_uint(y2.x) | __float_as_uint(y2.y)
             | __float_as_uint(y2.z) | __float_as_uint(y2.w);
    }
    // 4 pipelined cross-lane reductions (independent chains)
    #pragma unroll
    for (int sh = 32; sh > 0; sh >>= 1) {
      d[0] += __shfl_xor(d[0], sh);
      d[1] += __shfl_xor(d[1], sh);
      d[2] += __shfl_xor(d[2], sh);
      d[3] += __shfl_xor(d[3], sh);
    }
    float l[4];
    #pragma unroll
    for (int t = 0; t < 4; ++t) {
      int anynz = __any((int)(nzb[t] != 0u));
      wnz |= anynz;
      l[t] = anynz ? d[t] : d[t] + NEGBIG;
    }
    // group softmax
    float m4 = fmaxf(fmaxf(l[0], l[1]), fmaxf(l[2], l[3]));
    float e0 = __expf(l[0] - m4), e1 = __expf(l[1] - m4);
    float e2 = __expf(l[2] - m4), e3 = __expf(l[3] - m4);
    float s4 = (e0 + e1) + (e2 + e3);
    // single merge with running state
    float mn = fmaxf(m, m4);
    float sc = __expf(m - mn);
    float g4 = __expf(m4 - mn);
    s = s * sc + g4 * s4;
    float c0 = g4 * e0, c1 = g4 * e1, c2 = g4 * e2, c3 = g4 * e3;
    a0 = mul4(a0, sc); a1 = mul4(a1, sc); a2 = mul4(a2, sc);
    a0 = fma4(x0[0], c0, a0); a1 = fma4(x1[0], c0, a1); a2 = fma4(x2[0], c0, a2);
    a0 = fma4(x0[1], c1, a0); a1 = fma4(x1[1], c1, a1); a2 = fma4(x2[1], c1, a2);
    a0 = fma4(x0[2], c2, a0); a1 = fma4(x1[2], c2, a1); a2 = fma4(x2[2], c2, a2);
    a0 = fma4(x0[3], c3, a0); a1 = fma4(x1[3], c3, a1); a2 = fma4(x2[3], c3, a2);
    m = mn;
  }

  // ---- cross-wave merge ----
  __shared__ float m_lds[4], s_lds[4];
  __shared__ int   nz_lds[4];
  __shared__ float acc_lds[4 * 768];   // 12 KB

  if (lane == 0) { m_lds[wave] = m; nz_lds[wave] = wnz; }
  __syncthreads();
  float M = fmaxf(fmaxf(m_lds[0], m_lds[1]), fmaxf(m_lds[2], m_lds[3]));
  float scale = __expf(m - M);
  if (lane == 0) s_lds[wave] = s * scale;
  float4* al = (float4*)acc_lds;
  al[wave * 192 +       lane] = mul4(a0, scale);
  al[wave * 192 +  64 + lane] = mul4(a1, scale);
  al[wave * 192 + 128 + lane] = mul4(a2, scale);
  __syncthreads();

  if (tid < 192) {
    float4 A = add4(add4(al[tid], al[192 + tid]),
                    add4(al[384 + tid], al[576 + tid]));
    float S = s_lds[0] + s_lds[1] + s_lds[2] + s_lds[3];
    int has = nz_lds[0] | nz_lds[1] | nz_lds[2] | nz_lds[3];
    float4 r;
    if (has) { float inv = 1.f / S; r = mul4(A, inv); }
    else     { r = ((const float4*)empty_attr)[tid]; }
    ushort4 o;
    o.x = f2bf(r.x); o.y = f2bf(r.y); o.z = f2bf(r.z); o.w = f2bf(r.w);
    size_t base = ((size_t)b * 8 + side * 4 + f) * 192;
    ((ushort4*)concat)[base + tid] = o;
  }
}

// ---------------- GEMM1 split-K ----------------
// A [256,6144] bf16 (K-contig). W1 [1600,6144] f32 (K-contig).
// Grid (100 col-tiles, 8 K-chunks). Each block stages its EXCLUSIVE
// 16col x 768K W1 tile in LDS (bf16) -> W1 read once total.
__global__ __launch_bounds__(256) void gemm1_kernel(
    const unsigned short* __restrict__ A,
    const float* __restrict__ W1,
    float* __restrict__ Hpart)
{
  const int K = 6144, N = 1600, KC = 768;
  int colb = blockIdx.x;          // 0..99
  int kc   = blockIdx.y;          // 0..7
  int col0 = colb * 16;
  int tid = threadIdx.x, wave = tid >> 6, lane = tid & 63;

  __shared__ short wlds[96 * 16 * 8];

  const float* wsrc = W1 + (size_t)col0 * K + kc * KC;
  #pragma unroll
  for (int i = 0; i < 12; ++i) {
    int flat4 = tid + 256 * i;
    int col = flat4 / 192;
    int k   = (flat4 % 192) * 4;
    float4 w = *(const float4*)(wsrc + (size_t)col * K + k);
    short4_t o;
    o[0] = (short)f2bf(w.x); o[1] = (short)f2bf(w.y);
    o[2] = (short)f2bf(w.z); o[3] = (short)f2bf(w.w);
    *(short4_t*)(wlds + (k >> 3) * 128 + col * 8 + (k & 7)) = o;
  }
  __syncthreads();

  int lr = lane & 15;
  const short* a0 = (const short*)A + (size_t)(wave * 64 + lr) * K + kc * KC + (lane >> 4) * 8;
  const short* bptr = wlds + (lane >> 4) * 128 + lr * 8;

  f32x4 acc0 = {}, acc1 = {}, acc2 = {}, acc3 = {};

  #pragma unroll 4
  for (int ks = 0; ks < 24; ++ks) {
    short8 bf  = *(const short8*)(bptr + ks * 512);
    short8 af0 = *(const short8*)(a0 + ks * 32);
    short8 af1 = *(const short8*)(a0 + ks * 32 + 16 * K);
    short8 af2 = *(const short8*)(a0 + ks * 32 + 32 * K);
    short8 af3 = *(const short8*)(a0 + ks * 32 + 48 * K);
    acc0 = __builtin_amdgcn_mfma_f32_16x16x32_bf16(af0, bf, acc0, 0, 0, 0);
    acc1 = __builtin_amdgcn_mfma_f32_16x16x32_bf16(af1, bf, acc1, 0, 0, 0);
    acc2 = __builtin_amdgcn_mfma_f32_16x16x32_bf16(af2, bf, acc2, 0, 0, 0);
    acc3 = __builtin_amdgcn_mfma_f32_16x16x32_bf16(af3, bf, acc3, 0, 0, 0);
  }

  int ccol = lane & 15;
  int crow = (lane >> 4) * 4;
  float* hp = Hpart + (size_t)kc * 256 * N + (size_t)col0 + ccol;
  f32x4 accs[4] = {acc0, acc1, acc2, acc3};
  #pragma unroll
  for (int i = 0; i < 4; ++i) {
    int r = wave * 64 + i * 16 + crow;
    #pragma unroll
    for (int q = 0; q < 4; ++q)
      hp[(size_t)(r + q) * N] = accs[i][q];
  }
}

// ---------------- epilogue: reduce split-K + bias + relu + head GEMM -------
__global__ __launch_bounds__(256) void epilogue_kernel(
    const float* __restrict__ Hpart, const float* __restrict__ b1,
    const float* __restrict__ W2, const float* __restrict__ b2,
    float* __restrict__ out)
{
  const int N = 1600;
  int b = blockIdx.x, tid = threadIdx.x;
  int wave = tid >> 6, lane = tid & 63;
  float s0 = 0.f, s1 = 0.f;
  for (int c = tid; c < N; c += 256) {
    float acc = 0.f;
    #pragma unroll
    for (int kc = 0; kc < 8; ++kc)
      acc += Hpart[((size_t)kc * 256 + b) * N + c];
    float h = fmaxf(acc + b1[c], 0.f);
    s0 += h * W2[c];
    s1 += h * W2[N + c];
  }
  #pragma unroll
  for (int s = 32; s > 0; s >>= 1) {
    s0 += __shfl_xor(s0, s);
    s1 += __shfl_xor(s1, s);
  }
  __shared__ float r0[4], r1[4];
  if (lane == 0) { r0[wave] = s0; r1[wave] = s1; }
  __syncthreads();
  if (tid == 0) {
    out[b * 2 + 0] = r0[0] + r0[1] + r0[2] + r0[3] + b2[0];
    out[b * 2 + 1] = r1[0] + r1[1] + r1[2] + r1[3] + b2[1];
  }
}

extern "C" void kernel_launch(void* const* d_in, const int* in_sizes, int n_in,
                              void* d_out, int out_size, void* d_ws, size_t ws_size,
                              hipStream_t stream) {
  const float* left       = (const float*)d_in[0];
  const float* right      = (const float*)d_in[1];
  const float* femb_l     = (const float*)d_in[2];
  const float* femb_r     = (const float*)d_in[3];
  const float* empty_attr = (const float*)d_in[4];
  const float* W1         = (const float*)d_in[5];
  const float* b1         = (const float*)d_in[6];
  const float* W2         = (const float*)d_in[7];
  const float* b2         = (const float*)d_in[8];
  float* out = (float*)d_out;

  char* ws = (char*)d_ws;
  unsigned short* concat = (unsigned short*)ws;               // 256*6144*2 = 3,145,728 B
  float*          Hpart  = (float*)(ws + 3145728);            // 8*256*1600*4 = 13,107,200 B

  hipLaunchKernelGGL(pool_kernel, dim3(2048), dim3(256), 0, stream,
                     left, right, femb_l, femb_r, empty_attr, concat);
  hipLaunchKernelGGL(gemm1_kernel, dim3(100, 8), dim3(256), 0, stream,
                     concat, W1, Hpart);
  hipLaunchKernelGGL(epilogue_kernel, dim3(256), dim3(256), 0, stream,
                     Hpart, b1, W2, b2, out);
}

// Round 5
// 144.346 us; speedup vs baseline: 2.0796x; 2.0796x over previous
//
#include <hip/hip_runtime.h>

typedef __attribute__((ext_vector_type(8))) short short8;
typedef __attribute__((ext_vector_type(4))) short short4_t;
typedef __attribute__((ext_vector_type(4))) float f32x4;

#define NEGBIG -1e10f

__device__ __forceinline__ unsigned short f2bf(float x) {
  unsigned int u = __float_as_uint(x);
  u += 0x7FFFu + ((u >> 16) & 1u);          // round-to-nearest-even
  return (unsigned short)(u >> 16);
}
// pack two f32 -> bf16x2 (a in low16, b in high16), RNE
__device__ __forceinline__ unsigned pack2(float a, float b) {
  unsigned ua = __float_as_uint(a), ub = __float_as_uint(b);
  ua += 0x7FFFu + ((ua >> 16) & 1u);
  ub += 0x7FFFu + ((ub >> 16) & 1u);
  return (ua >> 16) | (ub & 0xFFFF0000u);
}
__device__ __forceinline__ float lo_bf(unsigned p) { return __uint_as_float(p << 16); }
__device__ __forceinline__ float hi_bf(unsigned p) { return __uint_as_float(p & 0xFFFF0000u); }

__device__ __forceinline__ float4 mul4(float4 a, float s) {
  float4 r; r.x = a.x*s; r.y = a.y*s; r.z = a.z*s; r.w = a.w*s; return r;
}
__device__ __forceinline__ float4 add4(float4 a, float4 b) {
  float4 r; r.x = a.x+b.x; r.y = a.y+b.y; r.z = a.z+b.z; r.w = a.w+b.w; return r;
}

// ---------------- pooling kernel ----------------
// One block (8 waves, 512 thr) per (side, b, f); wave owns 8 tokens.
// Phase 1: stream tokens once; keep only dot-partials + bf16-packed x in regs
//          (48 u32) -> nothing f32-large lives across the softmax.
// Phase 2: pipelined cross-lane reductions for all 8 logits at once.
// Phase 3: softmax (wave-local + one LDS merge), normalization folded into
//          a single per-wave scale applied after register accumulation.
__global__ __launch_bounds__(512, 3) void pool_kernel(
    const float* __restrict__ left, const float* __restrict__ right,
    const float* __restrict__ femb_l, const float* __restrict__ femb_r,
    const float* __restrict__ empty_attr,
    unsigned short* __restrict__ concat)   // [B, 8, 768] bf16
{
  int bid  = blockIdx.x;      // 0..2047
  int side = bid >> 10;       // 0 = left, 1 = right
  int rem  = bid & 1023;      // b*4 + f
  int f    = rem & 3;
  int b    = rem >> 2;
  const float* v    = (side ? right : left) + (size_t)rem * 64 * 768;
  const float* femb = (side ? femb_r : femb_l) + f * 768;

  int tid = threadIdx.x, wave = tid >> 6, lane = tid & 63;

  const float4* fp = (const float4*)femb;
  float4 f0 = fp[lane], f1 = fp[lane + 64], f2 = fp[lane + 128];

  const float4* vp = (const float4*)(v + (size_t)wave * 8 * 768);

  float d[8];
  unsigned pk0[8], pk1[8], pk2[8], pk3[8], pk4[8], pk5[8];
  unsigned nzmask = 0;

  // ---- Phase 1: stream 8 tokens; dot partial + bf16 pack ----
  #pragma unroll
  for (int t = 0; t < 8; ++t) {
    float4 x0 = vp[t * 192 + lane];
    float4 x1 = vp[t * 192 + 64 + lane];
    float4 x2 = vp[t * 192 + 128 + lane];
    d[t] = x0.x*f0.x + x0.y*f0.y + x0.z*f0.z + x0.w*f0.w
         + x1.x*f1.x + x1.y*f1.y + x1.z*f1.z + x1.w*f1.w
         + x2.x*f2.x + x2.y*f2.y + x2.z*f2.z + x2.w*f2.w;
    unsigned nzb = __float_as_uint(x0.x) | __float_as_uint(x0.y)
                 | __float_as_uint(x0.z) | __float_as_uint(x0.w)
                 | __float_as_uint(x1.x) | __float_as_uint(x1.y)
                 | __float_as_uint(x1.z) | __float_as_uint(x1.w)
                 | __float_as_uint(x2.x) | __float_as_uint(x2.y)
                 | __float_as_uint(x2.z) | __float_as_uint(x2.w);
    nzmask |= (nzb != 0u) ? (1u << t) : 0u;
    pk0[t] = pack2(x0.x, x0.y); pk1[t] = pack2(x0.z, x0.w);
    pk2[t] = pack2(x1.x, x1.y); pk3[t] = pack2(x1.z, x1.w);
    pk4[t] = pack2(x2.x, x2.y); pk5[t] = pack2(x2.z, x2.w);
  }

  // ---- Phase 2: 8 pipelined shuffle-reduce chains + nz OR-reduce ----
  #pragma unroll
  for (int sh = 32; sh > 0; sh >>= 1) {
    d[0] += __shfl_xor(d[0], sh);
    d[1] += __shfl_xor(d[1], sh);
    d[2] += __shfl_xor(d[2], sh);
    d[3] += __shfl_xor(d[3], sh);
    d[4] += __shfl_xor(d[4], sh);
    d[5] += __shfl_xor(d[5], sh);
    d[6] += __shfl_xor(d[6], sh);
    d[7] += __shfl_xor(d[7], sh);
    nzmask |= __shfl_xor(nzmask, sh);
  }

  // ---- Phase 3: softmax ----
  float l[8], e[8];
  #pragma unroll
  for (int t = 0; t < 8; ++t)
    l[t] = d[t] + (((nzmask >> t) & 1u) ? 0.f : NEGBIG);
  float m01 = fmaxf(l[0], l[1]), m23 = fmaxf(l[2], l[3]);
  float m45 = fmaxf(l[4], l[5]), m67 = fmaxf(l[6], l[7]);
  float m_w = fmaxf(fmaxf(m01, m23), fmaxf(m45, m67));
  #pragma unroll
  for (int t = 0; t < 8; ++t) e[t] = __expf(l[t] - m_w);
  float s_w = ((e[0]+e[1]) + (e[2]+e[3])) + ((e[4]+e[5]) + (e[6]+e[7]));

  __shared__ float m_lds[8], s_lds[8];
  __shared__ int   nz_lds[8];
  __shared__ float acc_lds[8 * 768];   // 24 KB

  if (lane == 0) { m_lds[wave] = m_w; s_lds[wave] = s_w; nz_lds[wave] = (nzmask != 0u); }

  // ---- accumulate from packed registers (independent of the merge) ----
  float4 A0 = {0,0,0,0}, A1 = {0,0,0,0}, A2 = {0,0,0,0};
  #pragma unroll
  for (int t = 0; t < 8; ++t) {
    float c = e[t];
    A0.x += c * lo_bf(pk0[t]); A0.y += c * hi_bf(pk0[t]);
    A0.z += c * lo_bf(pk1[t]); A0.w += c * hi_bf(pk1[t]);
    A1.x += c * lo_bf(pk2[t]); A1.y += c * hi_bf(pk2[t]);
    A1.z += c * lo_bf(pk3[t]); A1.w += c * hi_bf(pk3[t]);
    A2.x += c * lo_bf(pk4[t]); A2.y += c * hi_bf(pk4[t]);
    A2.z += c * lo_bf(pk5[t]); A2.w += c * hi_bf(pk5[t]);
  }

  __syncthreads();
  float M = m_lds[0];
  #pragma unroll
  for (int w = 1; w < 8; ++w) M = fmaxf(M, m_lds[w]);
  float S = 0.f;
  #pragma unroll
  for (int w = 0; w < 8; ++w) S += s_lds[w] * __expf(m_lds[w] - M);
  float scale = __expf(m_w - M) / S;

  float4* al = (float4*)acc_lds;
  al[wave * 192 +       lane] = mul4(A0, scale);
  al[wave * 192 +  64 + lane] = mul4(A1, scale);
  al[wave * 192 + 128 + lane] = mul4(A2, scale);
  __syncthreads();

  if (tid < 192) {
    float4 A = add4(add4(add4(al[tid], al[192 + tid]),
                         add4(al[384 + tid], al[576 + tid])),
                    add4(add4(al[768 + tid], al[960 + tid]),
                         add4(al[1152 + tid], al[1344 + tid])));
    int has = nz_lds[0] | nz_lds[1] | nz_lds[2] | nz_lds[3]
            | nz_lds[4] | nz_lds[5] | nz_lds[6] | nz_lds[7];
    float4 r;
    if (has) r = A;
    else     r = ((const float4*)empty_attr)[tid];
    ushort4 o;
    o.x = f2bf(r.x); o.y = f2bf(r.y); o.z = f2bf(r.z); o.w = f2bf(r.w);
    size_t base = ((size_t)b * 8 + side * 4 + f) * 192;
    ((ushort4*)concat)[base + tid] = o;
  }
}

// ---------------- GEMM1 split-K ----------------
// A [256,6144] bf16 (K-contig). W1 [1600,6144] f32 (K-contig).
// Grid (100 col-tiles, 8 K-chunks). Each block stages its EXCLUSIVE
// 16col x 768K W1 tile in LDS (bf16) -> W1 read once total.
__global__ __launch_bounds__(256) void gemm1_kernel(
    const unsigned short* __restrict__ A,
    const float* __restrict__ W1,
    float* __restrict__ Hpart)
{
  const int K = 6144, N = 1600, KC = 768;
  int colb = blockIdx.x;          // 0..99
  int kc   = blockIdx.y;          // 0..7
  int col0 = colb * 16;
  int tid = threadIdx.x, wave = tid >> 6, lane = tid & 63;

  __shared__ short wlds[96 * 16 * 8];

  const float* wsrc = W1 + (size_t)col0 * K + kc * KC;
  #pragma unroll
  for (int i = 0; i < 12; ++i) {
    int flat4 = tid + 256 * i;
    int col = flat4 / 192;
    int k   = (flat4 % 192) * 4;
    float4 w = *(const float4*)(wsrc + (size_t)col * K + k);
    short4_t o;
    o[0] = (short)f2bf(w.x); o[1] = (short)f2bf(w.y);
    o[2] = (short)f2bf(w.z); o[3] = (short)f2bf(w.w);
    *(short4_t*)(wlds + (k >> 3) * 128 + col * 8 + (k & 7)) = o;
  }
  __syncthreads();

  int lr = lane & 15;
  const short* a0 = (const short*)A + (size_t)(wave * 64 + lr) * K + kc * KC + (lane >> 4) * 8;
  const short* bptr = wlds + (lane >> 4) * 128 + lr * 8;

  f32x4 acc0 = {}, acc1 = {}, acc2 = {}, acc3 = {};

  #pragma unroll 4
  for (int ks = 0; ks < 24; ++ks) {
    short8 bf  = *(const short8*)(bptr + ks * 512);
    short8 af0 = *(const short8*)(a0 + ks * 32);
    short8 af1 = *(const short8*)(a0 + ks * 32 + 16 * K);
    short8 af2 = *(const short8*)(a0 + ks * 32 + 32 * K);
    short8 af3 = *(const short8*)(a0 + ks * 32 + 48 * K);
    acc0 = __builtin_amdgcn_mfma_f32_16x16x32_bf16(af0, bf, acc0, 0, 0, 0);
    acc1 = __builtin_amdgcn_mfma_f32_16x16x32_bf16(af1, bf, acc1, 0, 0, 0);
    acc2 = __builtin_amdgcn_mfma_f32_16x16x32_bf16(af2, bf, acc2, 0, 0, 0);
    acc3 = __builtin_amdgcn_mfma_f32_16x16x32_bf16(af3, bf, acc3, 0, 0, 0);
  }

  int ccol = lane & 15;
  int crow = (lane >> 4) * 4;
  float* hp = Hpart + (size_t)kc * 256 * N + (size_t)col0 + ccol;
  f32x4 accs[4] = {acc0, acc1, acc2, acc3};
  #pragma unroll
  for (int i = 0; i < 4; ++i) {
    int r = wave * 64 + i * 16 + crow;
    #pragma unroll
    for (int q = 0; q < 4; ++q)
      hp[(size_t)(r + q) * N] = accs[i][q];
  }
}

// ---------------- epilogue: reduce split-K + bias + relu + head GEMM -------
__global__ __launch_bounds__(256) void epilogue_kernel(
    const float* __restrict__ Hpart, const float* __restrict__ b1,
    const float* __restrict__ W2, const float* __restrict__ b2,
    float* __restrict__ out)
{
  const int N = 1600;
  int b = blockIdx.x, tid = threadIdx.x;
  int wave = tid >> 6, lane = tid & 63;
  float s0 = 0.f, s1 = 0.f;
  for (int c = tid; c < N; c += 256) {
    float acc = 0.f;
    #pragma unroll
    for (int kc = 0; kc < 8; ++kc)
      acc += Hpart[((size_t)kc * 256 + b) * N + c];
    float h = fmaxf(acc + b1[c], 0.f);
    s0 += h * W2[c];
    s1 += h * W2[N + c];
  }
  #pragma unroll
  for (int s = 32; s > 0; s >>= 1) {
    s0 += __shfl_xor(s0, s);
    s1 += __shfl_xor(s1, s);
  }
  __shared__ float r0[4], r1[4];
  if (lane == 0) { r0[wave] = s0; r1[wave] = s1; }
  __syncthreads();
  if (tid == 0) {
    out[b * 2 + 0] = r0[0] + r0[1] + r0[2] + r0[3] + b2[0];
    out[b * 2 + 1] = r1[0] + r1[1] + r1[2] + r1[3] + b2[1];
  }
}

extern "C" void kernel_launch(void* const* d_in, const int* in_sizes, int n_in,
                              void* d_out, int out_size, void* d_ws, size_t ws_size,
                              hipStream_t stream) {
  const float* left       = (const float*)d_in[0];
  const float* right      = (const float*)d_in[1];
  const float* femb_l     = (const float*)d_in[2];
  const float* femb_r     = (const float*)d_in[3];
  const float* empty_attr = (const float*)d_in[4];
  const float* W1         = (const float*)d_in[5];
  const float* b1         = (const float*)d_in[6];
  const float* W2         = (const float*)d_in[7];
  const float* b2         = (const float*)d_in[8];
  float* out = (float*)d_out;

  char* ws = (char*)d_ws;
  unsigned short* concat = (unsigned short*)ws;               // 256*6144*2 = 3,145,728 B
  float*          Hpart  = (float*)(ws + 3145728);            // 8*256*1600*4 = 13,107,200 B

  hipLaunchKernelGGL(pool_kernel, dim3(2048), dim3(512), 0, stream,
                     left, right, femb_l, femb_r, empty_attr, concat);
  hipLaunchKernelGGL(gemm1_kernel, dim3(100, 8), dim3(256), 0, stream,
                     concat, W1, Hpart);
  hipLaunchKernelGGL(epilogue_kernel, dim3(256), dim3(256), 0, stream,
                     Hpart, b1, W2, b2, out);
}

// Round 6
// 139.601 us; speedup vs baseline: 2.1503x; 1.0340x over previous
//
#include <hip/hip_runtime.h>

typedef __attribute__((ext_vector_type(8))) short short8;
typedef __attribute__((ext_vector_type(4))) short short4_t;
typedef __attribute__((ext_vector_type(4))) float f32x4;

#define NEGBIG -1e10f

__device__ __forceinline__ unsigned short f2bf(float x) {
  unsigned int u = __float_as_uint(x);
  u += 0x7FFFu + ((u >> 16) & 1u);          // round-to-nearest-even
  return (unsigned short)(u >> 16);
}
// pack two f32 -> bf16x2 (a in low16, b in high16), RNE
__device__ __forceinline__ unsigned pack2(float a, float b) {
  unsigned ua = __float_as_uint(a), ub = __float_as_uint(b);
  ua += 0x7FFFu + ((ua >> 16) & 1u);
  ub += 0x7FFFu + ((ub >> 16) & 1u);
  return (ua >> 16) | (ub & 0xFFFF0000u);
}
__device__ __forceinline__ float lo_bf(unsigned p) { return __uint_as_float(p << 16); }
__device__ __forceinline__ float hi_bf(unsigned p) { return __uint_as_float(p & 0xFFFF0000u); }

__device__ __forceinline__ float4 mul4(float4 a, float s) {
  float4 r; r.x = a.x*s; r.y = a.y*s; r.z = a.z*s; r.w = a.w*s; return r;
}
__device__ __forceinline__ float4 add4(float4 a, float4 b) {
  float4 r; r.x = a.x+b.x; r.y = a.y+b.y; r.z = a.z+b.z; r.w = a.w+b.w; return r;
}

// ---------------- pool partial: half-panel flash partials ----------------
// Grid 4096 = 2048 panels x 2 halves. Block = 4 waves (256 thr); wave owns
// 8 tokens (R5's proven register scheme: dot + bf16-pack, 72 VGPR, no spill).
// Emits UNNORMALIZED acc[768] w.r.t. block max M, plus (M, S, nz) meta.
// Small blocks -> ~7 blocks/CU resident (TLP hides the token-chain latency).
__global__ __launch_bounds__(256) void pool_partial(
    const float* __restrict__ left, const float* __restrict__ right,
    const float* __restrict__ femb_l, const float* __restrict__ femb_r,
    float* __restrict__ partials,      // [4096][768]
    float4* __restrict__ meta)         // [4096] (M, S, nz, 0)
{
  int bid   = blockIdx.x;     // 0..4095
  int panel = bid >> 1;       // 0..2047
  int half  = bid & 1;
  int side  = panel >> 10;
  int rem   = panel & 1023;   // b*4 + f
  int f     = rem & 3;
  const float* v    = (side ? right : left) + (size_t)rem * 64 * 768 + (size_t)half * 32 * 768;
  const float* femb = (side ? femb_r : femb_l) + f * 768;

  int tid = threadIdx.x, wave = tid >> 6, lane = tid & 63;

  const float4* fp = (const float4*)femb;
  float4 f0 = fp[lane], f1 = fp[lane + 64], f2 = fp[lane + 128];

  const float4* vp = (const float4*)(v + (size_t)wave * 8 * 768);

  float d[8];
  unsigned pk0[8], pk1[8], pk2[8], pk3[8], pk4[8], pk5[8];
  unsigned nzmask = 0;

  // ---- Phase 1: stream 8 tokens; dot partial + bf16 pack ----
  #pragma unroll
  for (int t = 0; t < 8; ++t) {
    float4 x0 = vp[t * 192 + lane];
    float4 x1 = vp[t * 192 + 64 + lane];
    float4 x2 = vp[t * 192 + 128 + lane];
    d[t] = x0.x*f0.x + x0.y*f0.y + x0.z*f0.z + x0.w*f0.w
         + x1.x*f1.x + x1.y*f1.y + x1.z*f1.z + x1.w*f1.w
         + x2.x*f2.x + x2.y*f2.y + x2.z*f2.z + x2.w*f2.w;
    unsigned nzb = __float_as_uint(x0.x) | __float_as_uint(x0.y)
                 | __float_as_uint(x0.z) | __float_as_uint(x0.w)
                 | __float_as_uint(x1.x) | __float_as_uint(x1.y)
                 | __float_as_uint(x1.z) | __float_as_uint(x1.w)
                 | __float_as_uint(x2.x) | __float_as_uint(x2.y)
                 | __float_as_uint(x2.z) | __float_as_uint(x2.w);
    nzmask |= (nzb != 0u) ? (1u << t) : 0u;
    pk0[t] = pack2(x0.x, x0.y); pk1[t] = pack2(x0.z, x0.w);
    pk2[t] = pack2(x1.x, x1.y); pk3[t] = pack2(x1.z, x1.w);
    pk4[t] = pack2(x2.x, x2.y); pk5[t] = pack2(x2.z, x2.w);
  }

  // ---- Phase 2: 8 pipelined shuffle-reduce chains + nz OR-reduce ----
  #pragma unroll
  for (int sh = 32; sh > 0; sh >>= 1) {
    d[0] += __shfl_xor(d[0], sh);
    d[1] += __shfl_xor(d[1], sh);
    d[2] += __shfl_xor(d[2], sh);
    d[3] += __shfl_xor(d[3], sh);
    d[4] += __shfl_xor(d[4], sh);
    d[5] += __shfl_xor(d[5], sh);
    d[6] += __shfl_xor(d[6], sh);
    d[7] += __shfl_xor(d[7], sh);
    nzmask |= __shfl_xor(nzmask, sh);
  }

  // ---- Phase 3: wave-local softmax pieces ----
  float l[8], e[8];
  #pragma unroll
  for (int t = 0; t < 8; ++t)
    l[t] = d[t] + (((nzmask >> t) & 1u) ? 0.f : NEGBIG);
  float m01 = fmaxf(l[0], l[1]), m23 = fmaxf(l[2], l[3]);
  float m45 = fmaxf(l[4], l[5]), m67 = fmaxf(l[6], l[7]);
  float m_w = fmaxf(fmaxf(m01, m23), fmaxf(m45, m67));
  #pragma unroll
  for (int t = 0; t < 8; ++t) e[t] = __expf(l[t] - m_w);
  float s_w = ((e[0]+e[1]) + (e[2]+e[3])) + ((e[4]+e[5]) + (e[6]+e[7]));

  __shared__ float m_lds[4], s_lds[4];
  __shared__ int   nz_lds[4];
  __shared__ float acc_lds[4 * 768];   // 12 KB

  if (lane == 0) { m_lds[wave] = m_w; s_lds[wave] = s_w; nz_lds[wave] = (nzmask != 0u); }

  // ---- accumulate from packed registers (independent of the merge) ----
  float4 A0 = {0,0,0,0}, A1 = {0,0,0,0}, A2 = {0,0,0,0};
  #pragma unroll
  for (int t = 0; t < 8; ++t) {
    float c = e[t];
    A0.x += c * lo_bf(pk0[t]); A0.y += c * hi_bf(pk0[t]);
    A0.z += c * lo_bf(pk1[t]); A0.w += c * hi_bf(pk1[t]);
    A1.x += c * lo_bf(pk2[t]); A1.y += c * hi_bf(pk2[t]);
    A1.z += c * lo_bf(pk3[t]); A1.w += c * hi_bf(pk3[t]);
    A2.x += c * lo_bf(pk4[t]); A2.y += c * hi_bf(pk4[t]);
    A2.z += c * lo_bf(pk5[t]); A2.w += c * hi_bf(pk5[t]);
  }

  __syncthreads();
  float M = fmaxf(fmaxf(m_lds[0], m_lds[1]), fmaxf(m_lds[2], m_lds[3]));
  float S = s_lds[0] * __expf(m_lds[0] - M) + s_lds[1] * __expf(m_lds[1] - M)
          + s_lds[2] * __expf(m_lds[2] - M) + s_lds[3] * __expf(m_lds[3] - M);
  float scale = __expf(m_w - M);   // unnormalized: keep S in meta

  float4* al = (float4*)acc_lds;
  al[wave * 192 +       lane] = mul4(A0, scale);
  al[wave * 192 +  64 + lane] = mul4(A1, scale);
  al[wave * 192 + 128 + lane] = mul4(A2, scale);
  __syncthreads();

  if (tid < 192) {
    float4 A = add4(add4(al[tid], al[192 + tid]),
                    add4(al[384 + tid], al[576 + tid]));
    ((float4*)(partials + (size_t)bid * 768))[tid] = A;
  }
  if (tid == 192) {
    int has = nz_lds[0] | nz_lds[1] | nz_lds[2] | nz_lds[3];
    float4 mt; mt.x = M; mt.y = S; mt.z = has ? 1.f : 0.f; mt.w = 0.f;
    meta[bid] = mt;
  }
}

// ---------------- pool merge: combine 2 half-panels, normalize, -> bf16 ----
__global__ __launch_bounds__(192) void pool_merge(
    const float* __restrict__ partials, const float4* __restrict__ meta,
    const float* __restrict__ empty_attr,
    unsigned short* __restrict__ concat)   // [B, 8, 768] bf16
{
  int panel = blockIdx.x;     // 0..2047
  int tid = threadIdx.x;      // 0..191
  int side = panel >> 10;
  int rem  = panel & 1023;
  int f    = rem & 3;
  int b    = rem >> 2;

  float4 mt0 = meta[panel * 2], mt1 = meta[panel * 2 + 1];
  float M = fmaxf(mt0.x, mt1.x);
  float sc0 = __expf(mt0.x - M), sc1 = __expf(mt1.x - M);
  float S = mt0.y * sc0 + mt1.y * sc1;
  int has = (mt0.z != 0.f) | (mt1.z != 0.f);

  float4 A0 = ((const float4*)(partials + (size_t)(panel * 2) * 768))[tid];
  float4 A1 = ((const float4*)(partials + (size_t)(panel * 2 + 1) * 768))[tid];
  float4 r;
  if (has) {
    float inv = 1.f / S;
    r = add4(mul4(A0, sc0 * inv), mul4(A1, sc1 * inv));
  } else {
    r = ((const float4*)empty_attr)[tid];
  }
  ushort4 o;
  o.x = f2bf(r.x); o.y = f2bf(r.y); o.z = f2bf(r.z); o.w = f2bf(r.w);
  size_t base = ((size_t)b * 8 + side * 4 + f) * 192;
  ((ushort4*)concat)[base + tid] = o;
}

// ---------------- GEMM1 split-K ----------------
// A [256,6144] bf16 (K-contig). W1 [1600,6144] f32 (K-contig).
// Grid (100 col-tiles, 8 K-chunks). Each block stages its EXCLUSIVE
// 16col x 768K W1 tile in LDS (bf16) -> W1 read once total.
__global__ __launch_bounds__(256) void gemm1_kernel(
    const unsigned short* __restrict__ A,
    const float* __restrict__ W1,
    float* __restrict__ Hpart)
{
  const int K = 6144, N = 1600, KC = 768;
  int colb = blockIdx.x;          // 0..99
  int kc   = blockIdx.y;          // 0..7
  int col0 = colb * 16;
  int tid = threadIdx.x, wave = tid >> 6, lane = tid & 63;

  __shared__ short wlds[96 * 16 * 8];

  const float* wsrc = W1 + (size_t)col0 * K + kc * KC;
  #pragma unroll
  for (int i = 0; i < 12; ++i) {
    int flat4 = tid + 256 * i;
    int col = flat4 / 192;
    int k   = (flat4 % 192) * 4;
    float4 w = *(const float4*)(wsrc + (size_t)col * K + k);
    short4_t o;
    o[0] = (short)f2bf(w.x); o[1] = (short)f2bf(w.y);
    o[2] = (short)f2bf(w.z); o[3] = (short)f2bf(w.w);
    *(short4_t*)(wlds + (k >> 3) * 128 + col * 8 + (k & 7)) = o;
  }
  __syncthreads();

  int lr = lane & 15;
  const short* a0 = (const short*)A + (size_t)(wave * 64 + lr) * K + kc * KC + (lane >> 4) * 8;
  const short* bptr = wlds + (lane >> 4) * 128 + lr * 8;

  f32x4 acc0 = {}, acc1 = {}, acc2 = {}, acc3 = {};

  #pragma unroll 4
  for (int ks = 0; ks < 24; ++ks) {
    short8 bf  = *(const short8*)(bptr + ks * 512);
    short8 af0 = *(const short8*)(a0 + ks * 32);
    short8 af1 = *(const short8*)(a0 + ks * 32 + 16 * K);
    short8 af2 = *(const short8*)(a0 + ks * 32 + 32 * K);
    short8 af3 = *(const short8*)(a0 + ks * 32 + 48 * K);
    acc0 = __builtin_amdgcn_mfma_f32_16x16x32_bf16(af0, bf, acc0, 0, 0, 0);
    acc1 = __builtin_amdgcn_mfma_f32_16x16x32_bf16(af1, bf, acc1, 0, 0, 0);
    acc2 = __builtin_amdgcn_mfma_f32_16x16x32_bf16(af2, bf, acc2, 0, 0, 0);
    acc3 = __builtin_amdgcn_mfma_f32_16x16x32_bf16(af3, bf, acc3, 0, 0, 0);
  }

  int ccol = lane & 15;
  int crow = (lane >> 4) * 4;
  float* hp = Hpart + (size_t)kc * 256 * N + (size_t)col0 + ccol;
  f32x4 accs[4] = {acc0, acc1, acc2, acc3};
  #pragma unroll
  for (int i = 0; i < 4; ++i) {
    int r = wave * 64 + i * 16 + crow;
    #pragma unroll
    for (int q = 0; q < 4; ++q)
      hp[(size_t)(r + q) * N] = accs[i][q];
  }
}

// ---------------- epilogue: reduce split-K + bias + relu + head GEMM -------
__global__ __launch_bounds__(256) void epilogue_kernel(
    const float* __restrict__ Hpart, const float* __restrict__ b1,
    const float* __restrict__ W2, const float* __restrict__ b2,
    float* __restrict__ out)
{
  const int N = 1600;
  int b = blockIdx.x, tid = threadIdx.x;
  int wave = tid >> 6, lane = tid & 63;
  float s0 = 0.f, s1 = 0.f;
  for (int c = tid; c < N; c += 256) {
    float acc = 0.f;
    #pragma unroll
    for (int kc = 0; kc < 8; ++kc)
      acc += Hpart[((size_t)kc * 256 + b) * N + c];
    float h = fmaxf(acc + b1[c], 0.f);
    s0 += h * W2[c];
    s1 += h * W2[N + c];
  }
  #pragma unroll
  for (int s = 32; s > 0; s >>= 1) {
    s0 += __shfl_xor(s0, s);
    s1 += __shfl_xor(s1, s);
  }
  __shared__ float r0[4], r1[4];
  if (lane == 0) { r0[wave] = s0; r1[wave] = s1; }
  __syncthreads();
  if (tid == 0) {
    out[b * 2 + 0] = r0[0] + r0[1] + r0[2] + r0[3] + b2[0];
    out[b * 2 + 1] = r1[0] + r1[1] + r1[2] + r1[3] + b2[1];
  }
}

extern "C" void kernel_launch(void* const* d_in, const int* in_sizes, int n_in,
                              void* d_out, int out_size, void* d_ws, size_t ws_size,
                              hipStream_t stream) {
  const float* left       = (const float*)d_in[0];
  const float* right      = (const float*)d_in[1];
  const float* femb_l     = (const float*)d_in[2];
  const float* femb_r     = (const float*)d_in[3];
  const float* empty_attr = (const float*)d_in[4];
  const float* W1         = (const float*)d_in[5];
  const float* b1         = (const float*)d_in[6];
  const float* W2         = (const float*)d_in[7];
  const float* b2         = (const float*)d_in[8];
  float* out = (float*)d_out;

  char* ws = (char*)d_ws;
  unsigned short* concat = (unsigned short*)ws;               // [0, 3.15MB)
  float*          Hpart  = (float*)(ws + 3145728);            // [3.15MB, 16.25MB) 8*256*1600*4
  // partials/meta ALIAS Hpart's region (consumed by pool_merge before
  // gemm1 writes Hpart; stream-serial so no hazard):
  float*  partials = Hpart;                                    // 4096*768*4 = 12,582,912 B
  float4* meta     = (float4*)(ws + 3145728 + 12582912);       // 4096*16 = 65,536 B

  hipLaunchKernelGGL(pool_partial, dim3(4096), dim3(256), 0, stream,
                     left, right, femb_l, femb_r, partials, meta);
  hipLaunchKernelGGL(pool_merge, dim3(2048), dim3(192), 0, stream,
                     partials, meta, empty_attr, concat);
  hipLaunchKernelGGL(gemm1_kernel, dim3(100, 8), dim3(256), 0, stream,
                     concat, W1, Hpart);
  hipLaunchKernelGGL(epilogue_kernel, dim3(256), dim3(256), 0, stream,
                     Hpart, b1, W2, b2, out);
}